// Round 3
// baseline (358.782 us; speedup 1.0000x reference)
//
#include <hip/hip_runtime.h>

#define DD 768
#define HN 8
#define LL 4096
#define BB 32
#define CH 32            // chunks per batch row -> grid = BB*CH = 1024 blocks
#define RPC (LL / CH)    // 128 rows per chunk
#define TR 4             // rows per LDS tile
#define NT (RPC / TR)    // 32 tiles per block
#define PSTR 772         // per-(block,head) partial: S[768], se at [768]

// ---------------- kernel 0: centered qk0[h][d] = G[d] - mean_d(G), G = gamma1[d]*scale*sum_dh q*w
__global__ __launch_bounds__(768) void k_qk(const float* __restrict__ wkv,
                                            const float* __restrict__ query,
                                            const float* __restrict__ gamma1,
                                            float* __restrict__ qk) {
  int h = blockIdx.x;
  int d = threadIdx.x;
  const float* wbase = wkv + (size_t)h * 96 * DD + d;
  const float* qb = query + h * 96;
  float acc = 0.f;
  #pragma unroll 8
  for (int i = 0; i < 96; ++i) acc = fmaf(qb[i], wbase[(size_t)i * DD], acc);
  acc *= 0.10206207261596577f * gamma1[d];   // 96^-0.5 * gamma1
  __shared__ float wsum[12];
  __shared__ float meanv;
  float v = acc;
  #pragma unroll
  for (int off = 1; off < 64; off <<= 1) v += __shfl_xor(v, off, 64);
  if ((d & 63) == 0) wsum[d >> 6] = v;
  __syncthreads();
  if (d == 0) {
    float s = 0.f;
    #pragma unroll
    for (int i = 0; i < 12; ++i) s += wsum[i];
    meanv = s * (1.f / 768.f);
  }
  __syncthreads();
  qk[h * DD + d] = acc - meanv;
}

// ---------------- kernel 1: LDS-tiled streaming; wave w owns heads {2w, 2w+1}
__global__ __launch_bounds__(256, 4) void k_main(
    const float* __restrict__ x, const float* __restrict__ qk,
    float* __restrict__ part) {
  const int tid  = threadIdx.x;
  const int lane = tid & 63;
  const int wave = tid >> 6;
  const int b     = blockIdx.x / CH;
  const int chunk = blockIdx.x - b * CH;
  const int h0 = wave * 2;

  __shared__ float lds[2][TR][DD];

  // qk fragments for the 2 owned heads (element j*256 + lane*4 + c)
  float4 qA[3], qB[3];
  #pragma unroll
  for (int j = 0; j < 3; ++j) {
    qA[j] = *reinterpret_cast<const float4*>(qk + h0 * DD + j * 256 + lane * 4);
    qB[j] = *reinterpret_cast<const float4*>(qk + (h0 + 1) * DD + j * 256 + lane * 4);
  }

  float4 SA[3], SB[3];
  #pragma unroll
  for (int j = 0; j < 3; ++j) {
    SA[j] = make_float4(0.f, 0.f, 0.f, 0.f);
    SB[j] = make_float4(0.f, 0.f, 0.f, 0.f);
  }
  float seA = 0.f, seB = 0.f, chA = 0.f, chB = 0.f;

  const float* gbase = x + ((size_t)b * LL + (size_t)chunk * RPC) * DD;
  const float4* g4 = reinterpret_cast<const float4*>(gbase);

  // two staging register sets (TR*DD/256 = 12 floats = 3 float4 per thread)
  float4 rA[3], rB[3];
  #pragma unroll
  for (int i = 0; i < 3; ++i) rA[i] = g4[i * 256 + tid];

  for (int t = 0; t < NT; ++t) {
    const int cur = t & 1;
    float4* lp = reinterpret_cast<float4*>(&lds[cur][0][0]);
    // commit staged regs for tile t
    if (cur == 0) {
      #pragma unroll
      for (int i = 0; i < 3; ++i) lp[i * 256 + tid] = rA[i];
    } else {
      #pragma unroll
      for (int i = 0; i < 3; ++i) lp[i * 256 + tid] = rB[i];
    }
    // issue tile t+1 global loads into the other set (covered by this tile's compute)
    if (t + 1 < NT) {
      const float4* gn = reinterpret_cast<const float4*>(gbase + (size_t)(t + 1) * TR * DD);
      if (cur == 0) {
        #pragma unroll
        for (int i = 0; i < 3; ++i) rB[i] = gn[i * 256 + tid];
      } else {
        #pragma unroll
        for (int i = 0; i < 3; ++i) rA[i] = gn[i * 256 + tid];
      }
    }
    __syncthreads();   // tile t visible; tile t+1 loads stay in flight

    #pragma unroll 1
    for (int r = 0; r < TR; ++r) {
      const float* row = &lds[cur][r][0];
      float4 c0 = *reinterpret_cast<const float4*>(row + lane * 4);
      float4 c1 = *reinterpret_cast<const float4*>(row + 256 + lane * 4);
      float4 c2 = *reinterpret_cast<const float4*>(row + 512 + lane * 4);

      float s1 = 0.f, s2 = 0.f, d0 = 0.f, d1 = 0.f;
#define ACC4(cv, J)                                                      \
      s1 += cv.x + cv.y + cv.z + cv.w;                                   \
      s2 = fmaf(cv.x, cv.x, s2); s2 = fmaf(cv.y, cv.y, s2);              \
      s2 = fmaf(cv.z, cv.z, s2); s2 = fmaf(cv.w, cv.w, s2);              \
      d0 = fmaf(cv.x, qA[J].x, d0); d0 = fmaf(cv.y, qA[J].y, d0);        \
      d0 = fmaf(cv.z, qA[J].z, d0); d0 = fmaf(cv.w, qA[J].w, d0);        \
      d1 = fmaf(cv.x, qB[J].x, d1); d1 = fmaf(cv.y, qB[J].y, d1);        \
      d1 = fmaf(cv.z, qB[J].z, d1); d1 = fmaf(cv.w, qB[J].w, d1);
      ACC4(c0, 0) ACC4(c1, 1) ACC4(c2, 2)
#undef ACC4

      #pragma unroll
      for (int off = 1; off < 64; off <<= 1) {
        s1 += __shfl_xor(s1, off, 64);
        s2 += __shfl_xor(s2, off, 64);
        d0 += __shfl_xor(d0, off, 64);
        d1 += __shfl_xor(d1, off, 64);
      }

      float mu   = s1 * (1.f / 768.f);
      float var  = fmaf(-mu, mu, s2 * (1.f / 768.f));
      float rstd = rsqrtf(var + 1e-5f);
      float sh   = -mu * rstd;
      float pe   = rstd * 1.44269504f;
      float p0 = exp2f(d0 * pe);
      float p1 = exp2f(d1 * pe);
      seA += p0; seB += p1;
      chA = fmaf(p0, sh, chA);
      chB = fmaf(p1, sh, chB);
      float a0 = p0 * rstd, a1 = p1 * rstd;

      SA[0].x = fmaf(a0, c0.x, SA[0].x); SA[0].y = fmaf(a0, c0.y, SA[0].y);
      SA[0].z = fmaf(a0, c0.z, SA[0].z); SA[0].w = fmaf(a0, c0.w, SA[0].w);
      SA[1].x = fmaf(a0, c1.x, SA[1].x); SA[1].y = fmaf(a0, c1.y, SA[1].y);
      SA[1].z = fmaf(a0, c1.z, SA[1].z); SA[1].w = fmaf(a0, c1.w, SA[1].w);
      SA[2].x = fmaf(a0, c2.x, SA[2].x); SA[2].y = fmaf(a0, c2.y, SA[2].y);
      SA[2].z = fmaf(a0, c2.z, SA[2].z); SA[2].w = fmaf(a0, c2.w, SA[2].w);

      SB[0].x = fmaf(a1, c0.x, SB[0].x); SB[0].y = fmaf(a1, c0.y, SB[0].y);
      SB[0].z = fmaf(a1, c0.z, SB[0].z); SB[0].w = fmaf(a1, c0.w, SB[0].w);
      SB[1].x = fmaf(a1, c1.x, SB[1].x); SB[1].y = fmaf(a1, c1.y, SB[1].y);
      SB[1].z = fmaf(a1, c1.z, SB[1].z); SB[1].w = fmaf(a1, c1.w, SB[1].w);
      SB[2].x = fmaf(a1, c2.x, SB[2].x); SB[2].y = fmaf(a1, c2.y, SB[2].y);
      SB[2].z = fmaf(a1, c2.z, SB[2].z); SB[2].w = fmaf(a1, c2.w, SB[2].w);
    }
  }

  // each head's state lives entirely in its owner wave -> direct global write
  size_t pb = (size_t)blockIdx.x * (HN * PSTR);
  float* pA = part + pb + (size_t)h0 * PSTR;
  float* pB = pA + PSTR;
  #pragma unroll
  for (int j = 0; j < 3; ++j) {
    float4 v = SA[j];
    v.x += chA; v.y += chA; v.z += chA; v.w += chA;
    *reinterpret_cast<float4*>(pA + j * 256 + lane * 4) = v;
    float4 w = SB[j];
    w.x += chB; w.y += chB; w.z += chB; w.w += chB;
    *reinterpret_cast<float4*>(pB + j * 256 + lane * 4) = w;
  }
  if (lane == 0) { pA[768] = seA; pB[768] = seB; }
}

// ---------------- kernel 2: combine partials -> xbar (gamma1/beta1) -> V-proj -> LN2
__global__ __launch_bounds__(1024) void k_fin(
    const float* __restrict__ part, const float* __restrict__ gamma1,
    const float* __restrict__ beta1, const float* __restrict__ wkv,
    const float* __restrict__ gamma2, const float* __restrict__ beta2,
    float* __restrict__ out, int chunksPerB) {
  int b = blockIdx.x;
  int t = threadIdx.x;
  __shared__ float xb[HN * DD];
  __shared__ float sed[HN];
  __shared__ float rs1[16], rs2[16];
  __shared__ float smu, srstd;
  const float* pb = part + (size_t)b * chunksPerB * HN * PSTR;

  if (t < HN) {
    float s = 0.f;
    for (int i = 0; i < chunksPerB; ++i)
      s += pb[(size_t)(i * HN + t) * PSTR + 768];
    sed[t] = 1.f / s;
  }
  __syncthreads();

  for (int e = t; e < HN * DD; e += 1024) {
    int h = e / DD, d = e - h * DD;
    float s = 0.f;
    for (int i = 0; i < chunksPerB; ++i)
      s += pb[(size_t)(i * HN + h) * PSTR + d];
    xb[e] = fmaf(gamma1[d], s * sed[h], beta1[d]);
  }
  __syncthreads();

  float o = 0.f;
  if (t < DD) {
    int h = t / 96;
    const float4* wrow = reinterpret_cast<const float4*>(wkv + (size_t)(DD + t) * DD);
    const float* xh = xb + h * DD;
    float acc = 0.f;
    #pragma unroll 4
    for (int e = 0; e < 192; ++e) {
      float4 w = wrow[e];
      acc = fmaf(w.x, xh[e * 4 + 0], acc);
      acc = fmaf(w.y, xh[e * 4 + 1], acc);
      acc = fmaf(w.z, xh[e * 4 + 2], acc);
      acc = fmaf(w.w, xh[e * 4 + 3], acc);
    }
    o = acc;
  }

  float v1 = (t < DD) ? o : 0.f;
  float v2 = v1 * v1;
  #pragma unroll
  for (int off = 1; off < 64; off <<= 1) {
    v1 += __shfl_xor(v1, off, 64);
    v2 += __shfl_xor(v2, off, 64);
  }
  int wv = t >> 6, ln = t & 63;
  if (ln == 0) { rs1[wv] = v1; rs2[wv] = v2; }
  __syncthreads();
  if (t == 0) {
    float s1 = 0.f, s2 = 0.f;
    #pragma unroll
    for (int w = 0; w < 16; ++w) { s1 += rs1[w]; s2 += rs2[w]; }
    float mu = s1 * (1.f / 768.f);
    float var = fmaf(-mu, mu, s2 * (1.f / 768.f));
    smu = mu;
    srstd = rsqrtf(var + 1e-5f);
  }
  __syncthreads();
  if (t < DD)
    out[(size_t)b * DD + t] = fmaf((o - smu) * srstd, gamma2[t], beta2[t]);
}

extern "C" void kernel_launch(void* const* d_in, const int* in_sizes, int n_in,
                              void* d_out, int out_size, void* d_ws, size_t ws_size,
                              hipStream_t stream) {
  const float* x     = (const float*)d_in[0];
  const float* wkv   = (const float*)d_in[1];
  const float* query = (const float*)d_in[2];
  const float* g1    = (const float*)d_in[3];
  const float* b1    = (const float*)d_in[4];
  const float* g2    = (const float*)d_in[5];
  const float* b2    = (const float*)d_in[6];
  float* out = (float*)d_out;
  float* ws  = (float*)d_ws;

  float* qk   = ws;          // 6144 floats (pad to 8192)
  float* part = ws + 8192;   // BB*CH*HN*PSTR floats (~25.3 MB)

  k_qk  <<<HN,      768,  0, stream>>>(wkv, query, g1, qk);
  k_main<<<BB * CH, 256,  0, stream>>>(x, qk, part);
  k_fin <<<BB,      1024, 0, stream>>>(part, g1, b1, wkv, g2, b2, out, CH);
}

// Round 4
// 329.674 us; speedup vs baseline: 1.0883x; 1.0883x over previous
//
#include <hip/hip_runtime.h>
#include <stdint.h>

#define DD 768
#define HN 8
#define LL 4096
#define BB 32
#define CH 32            // chunks per batch row -> grid = BB*CH = 1024 blocks
#define RPC (LL / CH)    // 128 rows per chunk
#define TR 4             // rows per LDS tile (12 KB tile, 24 KB double-buffered)
#define NT (RPC / TR)    // 32 tiles per block
#define PSTR 772         // per-(block,head) partial: S[768], se at [768]

#define GLOBAL_AS __attribute__((address_space(1)))
#define LDS_AS    __attribute__((address_space(3)))

// ---------------- kernel 0: centered qk0[h][d] = G[d] - mean_d(G), G = gamma1[d]*scale*sum_dh q*w
__global__ __launch_bounds__(768) void k_qk(const float* __restrict__ wkv,
                                            const float* __restrict__ query,
                                            const float* __restrict__ gamma1,
                                            float* __restrict__ qk) {
  int h = blockIdx.x;
  int d = threadIdx.x;
  const float* wbase = wkv + (size_t)h * 96 * DD + d;
  const float* qb = query + h * 96;
  float acc = 0.f;
  #pragma unroll 8
  for (int i = 0; i < 96; ++i) acc = fmaf(qb[i], wbase[(size_t)i * DD], acc);
  acc *= 0.10206207261596577f * gamma1[d];   // 96^-0.5 * gamma1
  __shared__ float wsum[12];
  __shared__ float meanv;
  float v = acc;
  #pragma unroll
  for (int off = 1; off < 64; off <<= 1) v += __shfl_xor(v, off, 64);
  if ((d & 63) == 0) wsum[d >> 6] = v;
  __syncthreads();
  if (d == 0) {
    float s = 0.f;
    #pragma unroll
    for (int i = 0; i < 12; ++i) s += wsum[i];
    meanv = s * (1.f / 768.f);
  }
  __syncthreads();
  qk[h * DD + d] = acc - meanv;
}

// ---------------- kernel 1: LDS double-buffered streaming via global_load_lds;
//                  wave w owns heads {2w, 2w+1}
__global__ __launch_bounds__(256, 4) void k_main(
    const float* __restrict__ x, const float* __restrict__ qk,
    float* __restrict__ part) {
  const int tid  = threadIdx.x;
  const int lane = tid & 63;
  const int wave = tid >> 6;
  const int b     = blockIdx.x / CH;
  const int chunk = blockIdx.x - b * CH;
  const int h0 = wave * 2;

  __shared__ float lds[2][TR][DD];

  // qk fragments for the 2 owned heads (element j*256 + lane*4 + c)
  float4 qA[3], qB[3];
  #pragma unroll
  for (int j = 0; j < 3; ++j) {
    qA[j] = *reinterpret_cast<const float4*>(qk + h0 * DD + j * 256 + lane * 4);
    qB[j] = *reinterpret_cast<const float4*>(qk + (h0 + 1) * DD + j * 256 + lane * 4);
  }

  float4 SA[3], SB[3];
  #pragma unroll
  for (int j = 0; j < 3; ++j) {
    SA[j] = make_float4(0.f, 0.f, 0.f, 0.f);
    SB[j] = make_float4(0.f, 0.f, 0.f, 0.f);
  }
  float seA = 0.f, seB = 0.f, chA = 0.f, chB = 0.f;

  const float* gbase = x + ((size_t)b * LL + (size_t)chunk * RPC) * DD;

  // stage tile t into buffer buf: 3x 16B DMA per thread, zero VGPR footprint.
  // LDS dest is wave-uniform base + lane*16 (linear); global src is per-lane.
  #define STAGE(T, BUF)                                                        \
    {                                                                          \
      const float* gt = gbase + (size_t)(T) * TR * DD;                         \
      float* lbase = &lds[(BUF)][0][0];                                        \
      _Pragma("unroll")                                                        \
      for (int i = 0; i < 3; ++i) {                                            \
        const float* src = gt + (size_t)(i * 256 + tid) * 4;                   \
        float* dst = lbase + (size_t)(i * 256 + wave * 64) * 4;                \
        __builtin_amdgcn_global_load_lds((const GLOBAL_AS uint32_t*)src,       \
                                         (LDS_AS uint32_t*)dst, 16, 0, 0);     \
      }                                                                        \
    }

  STAGE(0, 0)
  __syncthreads();   // vmcnt(0) drain -> tile 0 landed and visible

  for (int t = 0; t < NT; ++t) {
    const int cur = t & 1;
    // issue next tile's DMA first; it flies under this tile's compute
    if (t + 1 < NT) STAGE(t + 1, cur ^ 1)

    #pragma unroll 1
    for (int r = 0; r < TR; ++r) {
      const float* row = &lds[cur][r][0];
      float4 c0 = *reinterpret_cast<const float4*>(row + lane * 4);
      float4 c1 = *reinterpret_cast<const float4*>(row + 256 + lane * 4);
      float4 c2 = *reinterpret_cast<const float4*>(row + 512 + lane * 4);

      float s1 = 0.f, s2 = 0.f, d0 = 0.f, d1 = 0.f;
#define ACC4(cv, J)                                                      \
      s1 += cv.x + cv.y + cv.z + cv.w;                                   \
      s2 = fmaf(cv.x, cv.x, s2); s2 = fmaf(cv.y, cv.y, s2);              \
      s2 = fmaf(cv.z, cv.z, s2); s2 = fmaf(cv.w, cv.w, s2);              \
      d0 = fmaf(cv.x, qA[J].x, d0); d0 = fmaf(cv.y, qA[J].y, d0);        \
      d0 = fmaf(cv.z, qA[J].z, d0); d0 = fmaf(cv.w, qA[J].w, d0);        \
      d1 = fmaf(cv.x, qB[J].x, d1); d1 = fmaf(cv.y, qB[J].y, d1);        \
      d1 = fmaf(cv.z, qB[J].z, d1); d1 = fmaf(cv.w, qB[J].w, d1);
      ACC4(c0, 0) ACC4(c1, 1) ACC4(c2, 2)
#undef ACC4

      #pragma unroll
      for (int off = 1; off < 64; off <<= 1) {
        s1 += __shfl_xor(s1, off, 64);
        s2 += __shfl_xor(s2, off, 64);
        d0 += __shfl_xor(d0, off, 64);
        d1 += __shfl_xor(d1, off, 64);
      }

      float mu   = s1 * (1.f / 768.f);
      float var  = fmaf(-mu, mu, s2 * (1.f / 768.f));
      float rstd = rsqrtf(var + 1e-5f);
      float sh   = -mu * rstd;
      float pe   = rstd * 1.44269504f;
      float p0 = exp2f(d0 * pe);
      float p1 = exp2f(d1 * pe);
      seA += p0; seB += p1;
      chA = fmaf(p0, sh, chA);
      chB = fmaf(p1, sh, chB);
      float a0 = p0 * rstd, a1 = p1 * rstd;

      SA[0].x = fmaf(a0, c0.x, SA[0].x); SA[0].y = fmaf(a0, c0.y, SA[0].y);
      SA[0].z = fmaf(a0, c0.z, SA[0].z); SA[0].w = fmaf(a0, c0.w, SA[0].w);
      SA[1].x = fmaf(a0, c1.x, SA[1].x); SA[1].y = fmaf(a0, c1.y, SA[1].y);
      SA[1].z = fmaf(a0, c1.z, SA[1].z); SA[1].w = fmaf(a0, c1.w, SA[1].w);
      SA[2].x = fmaf(a0, c2.x, SA[2].x); SA[2].y = fmaf(a0, c2.y, SA[2].y);
      SA[2].z = fmaf(a0, c2.z, SA[2].z); SA[2].w = fmaf(a0, c2.w, SA[2].w);

      SB[0].x = fmaf(a1, c0.x, SB[0].x); SB[0].y = fmaf(a1, c0.y, SB[0].y);
      SB[0].z = fmaf(a1, c0.z, SB[0].z); SB[0].w = fmaf(a1, c0.w, SB[0].w);
      SB[1].x = fmaf(a1, c1.x, SB[1].x); SB[1].y = fmaf(a1, c1.y, SB[1].y);
      SB[1].z = fmaf(a1, c1.z, SB[1].z); SB[1].w = fmaf(a1, c1.w, SB[1].w);
      SB[2].x = fmaf(a1, c2.x, SB[2].x); SB[2].y = fmaf(a1, c2.y, SB[2].y);
      SB[2].z = fmaf(a1, c2.z, SB[2].z); SB[2].w = fmaf(a1, c2.w, SB[2].w);
    }
    __syncthreads();  // drains tile t+1 DMA (landed under compute) + buffer-reuse fence
  }
  #undef STAGE

  // each head's state lives entirely in its owner wave -> direct global write
  size_t pb = (size_t)blockIdx.x * (HN * PSTR);
  float* pA = part + pb + (size_t)h0 * PSTR;
  float* pB = pA + PSTR;
  #pragma unroll
  for (int j = 0; j < 3; ++j) {
    float4 v = SA[j];
    v.x += chA; v.y += chA; v.z += chA; v.w += chA;
    *reinterpret_cast<float4*>(pA + j * 256 + lane * 4) = v;
    float4 w = SB[j];
    w.x += chB; w.y += chB; w.z += chB; w.w += chB;
    *reinterpret_cast<float4*>(pB + j * 256 + lane * 4) = w;
  }
  if (lane == 0) { pA[768] = seA; pB[768] = seB; }
}

// ---------------- kernel 2: combine partials -> xbar (gamma1/beta1) -> V-proj -> LN2
__global__ __launch_bounds__(1024) void k_fin(
    const float* __restrict__ part, const float* __restrict__ gamma1,
    const float* __restrict__ beta1, const float* __restrict__ wkv,
    const float* __restrict__ gamma2, const float* __restrict__ beta2,
    float* __restrict__ out, int chunksPerB) {
  int b = blockIdx.x;
  int t = threadIdx.x;
  __shared__ float xb[HN * DD];
  __shared__ float sed[HN];
  __shared__ float rs1[16], rs2[16];
  __shared__ float smu, srstd;
  const float* pb = part + (size_t)b * chunksPerB * HN * PSTR;

  if (t < HN) {
    float s = 0.f;
    for (int i = 0; i < chunksPerB; ++i)
      s += pb[(size_t)(i * HN + t) * PSTR + 768];
    sed[t] = 1.f / s;
  }
  __syncthreads();

  for (int e = t; e < HN * DD; e += 1024) {
    int h = e / DD, d = e - h * DD;
    float s = 0.f;
    for (int i = 0; i < chunksPerB; ++i)
      s += pb[(size_t)(i * HN + h) * PSTR + d];
    xb[e] = fmaf(gamma1[d], s * sed[h], beta1[d]);
  }
  __syncthreads();

  float o = 0.f;
  if (t < DD) {
    int h = t / 96;
    const float4* wrow = reinterpret_cast<const float4*>(wkv + (size_t)(DD + t) * DD);
    const float* xh = xb + h * DD;
    float acc = 0.f;
    #pragma unroll 4
    for (int e = 0; e < 192; ++e) {
      float4 w = wrow[e];
      acc = fmaf(w.x, xh[e * 4 + 0], acc);
      acc = fmaf(w.y, xh[e * 4 + 1], acc);
      acc = fmaf(w.z, xh[e * 4 + 2], acc);
      acc = fmaf(w.w, xh[e * 4 + 3], acc);
    }
    o = acc;
  }

  float v1 = (t < DD) ? o : 0.f;
  float v2 = v1 * v1;
  #pragma unroll
  for (int off = 1; off < 64; off <<= 1) {
    v1 += __shfl_xor(v1, off, 64);
    v2 += __shfl_xor(v2, off, 64);
  }
  int wv = t >> 6, ln = t & 63;
  if (ln == 0) { rs1[wv] = v1; rs2[wv] = v2; }
  __syncthreads();
  if (t == 0) {
    float s1 = 0.f, s2 = 0.f;
    #pragma unroll
    for (int w = 0; w < 16; ++w) { s1 += rs1[w]; s2 += rs2[w]; }
    float mu = s1 * (1.f / 768.f);
    float var = fmaf(-mu, mu, s2 * (1.f / 768.f));
    smu = mu;
    srstd = rsqrtf(var + 1e-5f);
  }
  __syncthreads();
  if (t < DD)
    out[(size_t)b * DD + t] = fmaf((o - smu) * srstd, gamma2[t], beta2[t]);
}

extern "C" void kernel_launch(void* const* d_in, const int* in_sizes, int n_in,
                              void* d_out, int out_size, void* d_ws, size_t ws_size,
                              hipStream_t stream) {
  const float* x     = (const float*)d_in[0];
  const float* wkv   = (const float*)d_in[1];
  const float* query = (const float*)d_in[2];
  const float* g1    = (const float*)d_in[3];
  const float* b1    = (const float*)d_in[4];
  const float* g2    = (const float*)d_in[5];
  const float* b2    = (const float*)d_in[6];
  float* out = (float*)d_out;
  float* ws  = (float*)d_ws;

  float* qk   = ws;          // 6144 floats (pad to 8192)
  float* part = ws + 8192;   // BB*CH*HN*PSTR floats (~25.3 MB)

  k_qk  <<<HN,      768,  0, stream>>>(wkv, query, g1, qk);
  k_main<<<BB * CH, 256,  0, stream>>>(x, qk, part);
  k_fin <<<BB,      1024, 0, stream>>>(part, g1, b1, wkv, g2, b2, out, CH);
}

// Round 5
// 295.123 us; speedup vs baseline: 1.2157x; 1.1171x over previous
//
#include <hip/hip_runtime.h>
#include <stdint.h>

#define DD 768
#define HN 8
#define LL 4096
#define BB 32
#define CH 32            // chunks per batch row -> grid = BB*CH = 1024 blocks
#define RPC (LL / CH)    // 128 rows per chunk
#define TR 4             // rows per LDS tile (12 KB tile, 24 KB double-buffered)
#define NT (RPC / TR)    // 32 tiles per block
#define PSTR 772         // per-(block,head) partial: S[768], se at [768]

#define GLOBAL_AS __attribute__((address_space(1)))
#define LDS_AS    __attribute__((address_space(3)))

// ---- DPP wave64 sum helpers (gfx9 lineage): 6 adds, no LDS traffic ----
#define DPP_STEP(x, ctrl, rmask, bc)                                           \
  x += __int_as_float(__builtin_amdgcn_update_dpp(                             \
      0, __float_as_int(x), (ctrl), (rmask), 0xf, (bc)))

// reduce 4 independent values together (ILP-4 through the 6 dependent rounds);
// results become wave-uniform via readlane(63).
__device__ __forceinline__ void wave_sum4(float& a, float& b, float& c, float& d) {
  DPP_STEP(a, 0x111, 0xf, true);  DPP_STEP(b, 0x111, 0xf, true);
  DPP_STEP(c, 0x111, 0xf, true);  DPP_STEP(d, 0x111, 0xf, true);
  DPP_STEP(a, 0x112, 0xf, true);  DPP_STEP(b, 0x112, 0xf, true);
  DPP_STEP(c, 0x112, 0xf, true);  DPP_STEP(d, 0x112, 0xf, true);
  DPP_STEP(a, 0x114, 0xf, true);  DPP_STEP(b, 0x114, 0xf, true);
  DPP_STEP(c, 0x114, 0xf, true);  DPP_STEP(d, 0x114, 0xf, true);
  DPP_STEP(a, 0x118, 0xf, true);  DPP_STEP(b, 0x118, 0xf, true);
  DPP_STEP(c, 0x118, 0xf, true);  DPP_STEP(d, 0x118, 0xf, true);
  DPP_STEP(a, 0x142, 0xa, false); DPP_STEP(b, 0x142, 0xa, false);
  DPP_STEP(c, 0x142, 0xa, false); DPP_STEP(d, 0x142, 0xa, false);
  DPP_STEP(a, 0x143, 0xc, false); DPP_STEP(b, 0x143, 0xc, false);
  DPP_STEP(c, 0x143, 0xc, false); DPP_STEP(d, 0x143, 0xc, false);
  a = __int_as_float(__builtin_amdgcn_readlane(__float_as_int(a), 63));
  b = __int_as_float(__builtin_amdgcn_readlane(__float_as_int(b), 63));
  c = __int_as_float(__builtin_amdgcn_readlane(__float_as_int(c), 63));
  d = __int_as_float(__builtin_amdgcn_readlane(__float_as_int(d), 63));
}

// ---------------- kernel 0: centered qk0[h][d] = G[d] - mean_d(G), G = gamma1[d]*scale*sum_dh q*w
__global__ __launch_bounds__(768) void k_qk(const float* __restrict__ wkv,
                                            const float* __restrict__ query,
                                            const float* __restrict__ gamma1,
                                            float* __restrict__ qk) {
  int h = blockIdx.x;
  int d = threadIdx.x;
  const float* wbase = wkv + (size_t)h * 96 * DD + d;
  const float* qb = query + h * 96;
  float acc = 0.f;
  #pragma unroll 8
  for (int i = 0; i < 96; ++i) acc = fmaf(qb[i], wbase[(size_t)i * DD], acc);
  acc *= 0.10206207261596577f * gamma1[d];   // 96^-0.5 * gamma1
  __shared__ float wsum[12];
  __shared__ float meanv;
  float v = acc;
  #pragma unroll
  for (int off = 1; off < 64; off <<= 1) v += __shfl_xor(v, off, 64);
  if ((d & 63) == 0) wsum[d >> 6] = v;
  __syncthreads();
  if (d == 0) {
    float s = 0.f;
    #pragma unroll
    for (int i = 0; i < 12; ++i) s += wsum[i];
    meanv = s * (1.f / 768.f);
  }
  __syncthreads();
  qk[h * DD + d] = acc - meanv;
}

// ---------------- kernel 1: LDS double-buffered streaming via global_load_lds;
//                  wave w owns heads {2w, 2w+1}; DPP reductions (no shuffle LDS traffic)
__global__ __launch_bounds__(256, 4) void k_main(
    const float* __restrict__ x, const float* __restrict__ qk,
    float* __restrict__ part) {
  const int tid  = threadIdx.x;
  const int lane = tid & 63;
  const int wave = tid >> 6;
  const int b     = blockIdx.x / CH;
  const int chunk = blockIdx.x - b * CH;
  const int h0 = wave * 2;

  __shared__ float lds[2][TR][DD];

  float4 qA[3], qB[3];
  #pragma unroll
  for (int j = 0; j < 3; ++j) {
    qA[j] = *reinterpret_cast<const float4*>(qk + h0 * DD + j * 256 + lane * 4);
    qB[j] = *reinterpret_cast<const float4*>(qk + (h0 + 1) * DD + j * 256 + lane * 4);
  }

  float4 SA[3], SB[3];
  #pragma unroll
  for (int j = 0; j < 3; ++j) {
    SA[j] = make_float4(0.f, 0.f, 0.f, 0.f);
    SB[j] = make_float4(0.f, 0.f, 0.f, 0.f);
  }
  float seA = 0.f, seB = 0.f, chA = 0.f, chB = 0.f;

  const float* gbase = x + ((size_t)b * LL + (size_t)chunk * RPC) * DD;

  // stage tile T into buffer BUF: 3x 16B global->LDS DMA per thread, zero VGPRs
  #define STAGE(T, BUF)                                                        \
    {                                                                          \
      const float* gt = gbase + (size_t)(T) * TR * DD;                         \
      float* lbase = &lds[(BUF)][0][0];                                        \
      _Pragma("unroll")                                                        \
      for (int i = 0; i < 3; ++i) {                                            \
        const float* src = gt + (size_t)(i * 256 + tid) * 4;                   \
        float* dst = lbase + (size_t)(i * 256 + wave * 64) * 4;                \
        __builtin_amdgcn_global_load_lds((const GLOBAL_AS uint32_t*)src,       \
                                         (LDS_AS uint32_t*)dst, 16, 0, 0);     \
      }                                                                        \
    }

  STAGE(0, 0)
  __syncthreads();   // vmcnt(0) drain -> tile 0 landed and visible

  for (int t = 0; t < NT; ++t) {
    const int cur = t & 1;
    if (t + 1 < NT) STAGE(t + 1, cur ^ 1)   // flies under this tile's compute

    #pragma unroll 1
    for (int r = 0; r < TR; ++r) {
      const float* row = &lds[cur][r][0];
      float4 c0 = *reinterpret_cast<const float4*>(row + lane * 4);
      float4 c1 = *reinterpret_cast<const float4*>(row + 256 + lane * 4);
      float4 c2 = *reinterpret_cast<const float4*>(row + 512 + lane * 4);

      float s1 = 0.f, s2 = 0.f, d0 = 0.f, d1 = 0.f;
#define ACC4(cv, J)                                                      \
      s1 += cv.x + cv.y + cv.z + cv.w;                                   \
      s2 = fmaf(cv.x, cv.x, s2); s2 = fmaf(cv.y, cv.y, s2);              \
      s2 = fmaf(cv.z, cv.z, s2); s2 = fmaf(cv.w, cv.w, s2);              \
      d0 = fmaf(cv.x, qA[J].x, d0); d0 = fmaf(cv.y, qA[J].y, d0);        \
      d0 = fmaf(cv.z, qA[J].z, d0); d0 = fmaf(cv.w, qA[J].w, d0);        \
      d1 = fmaf(cv.x, qB[J].x, d1); d1 = fmaf(cv.y, qB[J].y, d1);        \
      d1 = fmaf(cv.z, qB[J].z, d1); d1 = fmaf(cv.w, qB[J].w, d1);
      ACC4(c0, 0) ACC4(c1, 1) ACC4(c2, 2)
#undef ACC4

      wave_sum4(s1, s2, d0, d1);   // DPP: VALU-only, results wave-uniform

      float mu   = s1 * (1.f / 768.f);
      float var  = fmaf(-mu, mu, s2 * (1.f / 768.f));
      float rstd = rsqrtf(var + 1e-5f);
      float sh   = -mu * rstd;
      float pe   = rstd * 1.44269504f;
      float p0 = exp2f(d0 * pe);
      float p1 = exp2f(d1 * pe);
      seA += p0; seB += p1;
      chA = fmaf(p0, sh, chA);
      chB = fmaf(p1, sh, chB);
      float a0 = p0 * rstd, a1 = p1 * rstd;

      SA[0].x = fmaf(a0, c0.x, SA[0].x); SA[0].y = fmaf(a0, c0.y, SA[0].y);
      SA[0].z = fmaf(a0, c0.z, SA[0].z); SA[0].w = fmaf(a0, c0.w, SA[0].w);
      SA[1].x = fmaf(a0, c1.x, SA[1].x); SA[1].y = fmaf(a0, c1.y, SA[1].y);
      SA[1].z = fmaf(a0, c1.z, SA[1].z); SA[1].w = fmaf(a0, c1.w, SA[1].w);
      SA[2].x = fmaf(a0, c2.x, SA[2].x); SA[2].y = fmaf(a0, c2.y, SA[2].y);
      SA[2].z = fmaf(a0, c2.z, SA[2].z); SA[2].w = fmaf(a0, c2.w, SA[2].w);

      SB[0].x = fmaf(a1, c0.x, SB[0].x); SB[0].y = fmaf(a1, c0.y, SB[0].y);
      SB[0].z = fmaf(a1, c0.z, SB[0].z); SB[0].w = fmaf(a1, c0.w, SB[0].w);
      SB[1].x = fmaf(a1, c1.x, SB[1].x); SB[1].y = fmaf(a1, c1.y, SB[1].y);
      SB[1].z = fmaf(a1, c1.z, SB[1].z); SB[1].w = fmaf(a1, c1.w, SB[1].w);
      SB[2].x = fmaf(a1, c2.x, SB[2].x); SB[2].y = fmaf(a1, c2.y, SB[2].y);
      SB[2].z = fmaf(a1, c2.z, SB[2].z); SB[2].w = fmaf(a1, c2.w, SB[2].w);
    }
    __syncthreads();  // drains next tile's DMA + buffer-reuse fence
  }
  #undef STAGE

  size_t pb = (size_t)blockIdx.x * (HN * PSTR);
  float* pA = part + pb + (size_t)h0 * PSTR;
  float* pB = pA + PSTR;
  #pragma unroll
  for (int j = 0; j < 3; ++j) {
    float4 v = SA[j];
    v.x += chA; v.y += chA; v.z += chA; v.w += chA;
    *reinterpret_cast<float4*>(pA + j * 256 + lane * 4) = v;
    float4 w = SB[j];
    w.x += chB; w.y += chB; w.z += chB; w.w += chB;
    *reinterpret_cast<float4*>(pB + j * 256 + lane * 4) = w;
  }
  if (lane == 0) { pA[768] = seA; pB[768] = seB; }
}

// ---------------- kernel 2: combine partials -> xbar (gamma1/beta1) -> V-proj -> LN2
__global__ __launch_bounds__(1024) void k_fin(
    const float* __restrict__ part, const float* __restrict__ gamma1,
    const float* __restrict__ beta1, const float* __restrict__ wkv,
    const float* __restrict__ gamma2, const float* __restrict__ beta2,
    float* __restrict__ out, int chunksPerB) {
  int b = blockIdx.x;
  int t = threadIdx.x;
  __shared__ float xb[HN * DD];
  __shared__ float sed[HN];
  __shared__ float rs1[16], rs2[16];
  __shared__ float smu, srstd;
  const float* pb = part + (size_t)b * chunksPerB * HN * PSTR;

  if (t < HN) {
    float s = 0.f;
    for (int i = 0; i < chunksPerB; ++i)
      s += pb[(size_t)(i * HN + t) * PSTR + 768];
    sed[t] = 1.f / s;
  }
  __syncthreads();

  for (int e = t; e < HN * DD; e += 1024) {
    int h = e / DD, d = e - h * DD;
    float s = 0.f;
    for (int i = 0; i < chunksPerB; ++i)
      s += pb[(size_t)(i * HN + h) * PSTR + d];
    xb[e] = fmaf(gamma1[d], s * sed[h], beta1[d]);
  }
  __syncthreads();

  float o = 0.f;
  if (t < DD) {
    int h = t / 96;
    const float4* wrow = reinterpret_cast<const float4*>(wkv + (size_t)(DD + t) * DD);
    const float* xh = xb + h * DD;
    float acc = 0.f;
    #pragma unroll 4
    for (int e = 0; e < 192; ++e) {
      float4 w = wrow[e];
      acc = fmaf(w.x, xh[e * 4 + 0], acc);
      acc = fmaf(w.y, xh[e * 4 + 1], acc);
      acc = fmaf(w.z, xh[e * 4 + 2], acc);
      acc = fmaf(w.w, xh[e * 4 + 3], acc);
    }
    o = acc;
  }

  float v1 = (t < DD) ? o : 0.f;
  float v2 = v1 * v1;
  #pragma unroll
  for (int off = 1; off < 64; off <<= 1) {
    v1 += __shfl_xor(v1, off, 64);
    v2 += __shfl_xor(v2, off, 64);
  }
  int wv = t >> 6, ln = t & 63;
  if (ln == 0) { rs1[wv] = v1; rs2[wv] = v2; }
  __syncthreads();
  if (t == 0) {
    float s1 = 0.f, s2 = 0.f;
    #pragma unroll
    for (int w = 0; w < 16; ++w) { s1 += rs1[w]; s2 += rs2[w]; }
    float mu = s1 * (1.f / 768.f);
    float var = fmaf(-mu, mu, s2 * (1.f / 768.f));
    smu = mu;
    srstd = rsqrtf(var + 1e-5f);
  }
  __syncthreads();
  if (t < DD)
    out[(size_t)b * DD + t] = fmaf((o - smu) * srstd, gamma2[t], beta2[t]);
}

extern "C" void kernel_launch(void* const* d_in, const int* in_sizes, int n_in,
                              void* d_out, int out_size, void* d_ws, size_t ws_size,
                              hipStream_t stream) {
  const float* x     = (const float*)d_in[0];
  const float* wkv   = (const float*)d_in[1];
  const float* query = (const float*)d_in[2];
  const float* g1    = (const float*)d_in[3];
  const float* b1    = (const float*)d_in[4];
  const float* g2    = (const float*)d_in[5];
  const float* b2    = (const float*)d_in[6];
  float* out = (float*)d_out;
  float* ws  = (float*)d_ws;

  float* qk   = ws;          // 6144 floats (pad to 8192)
  float* part = ws + 8192;   // BB*CH*HN*PSTR floats (~25.3 MB)

  k_qk  <<<HN,      768,  0, stream>>>(wkv, query, g1, qk);
  k_main<<<BB * CH, 256,  0, stream>>>(x, qk, part);
  k_fin <<<BB,      1024, 0, stream>>>(part, g1, b1, wkv, g2, b2, out, CH);
}

// Round 6
// 252.170 us; speedup vs baseline: 1.4228x; 1.1703x over previous
//
#include <hip/hip_runtime.h>
#include <stdint.h>

#define DD 768
#define HN 8
#define LL 4096
#define BB 32
#define CH 32            // chunks per batch row -> grid = BB*CH = 1024 blocks
#define RPC (LL / CH)    // 128 rows per chunk
#define TR 4             // rows per LDS tile (12 KB per buffer)
#define NB 3             // triple-buffered LDS (36 KB) -> 2-tile-deep prefetch
#define NT (RPC / TR)    // 32 tiles per block
#define PSTR 772         // per-(block,head) partial: S[768], se at [768]

#define GLOBAL_AS __attribute__((address_space(1)))
#define LDS_AS    __attribute__((address_space(3)))

// ---- DPP wave64 sum helpers: 6 rounds, VALU-only, 4-wide ILP ----
#define DPP_STEP(x, ctrl, rmask, bc)                                           \
  x += __int_as_float(__builtin_amdgcn_update_dpp(                             \
      0, __float_as_int(x), (ctrl), (rmask), 0xf, (bc)))

__device__ __forceinline__ void wave_sum4(float& a, float& b, float& c, float& d) {
  DPP_STEP(a, 0x111, 0xf, true);  DPP_STEP(b, 0x111, 0xf, true);
  DPP_STEP(c, 0x111, 0xf, true);  DPP_STEP(d, 0x111, 0xf, true);
  DPP_STEP(a, 0x112, 0xf, true);  DPP_STEP(b, 0x112, 0xf, true);
  DPP_STEP(c, 0x112, 0xf, true);  DPP_STEP(d, 0x112, 0xf, true);
  DPP_STEP(a, 0x114, 0xf, true);  DPP_STEP(b, 0x114, 0xf, true);
  DPP_STEP(c, 0x114, 0xf, true);  DPP_STEP(d, 0x114, 0xf, true);
  DPP_STEP(a, 0x118, 0xf, true);  DPP_STEP(b, 0x118, 0xf, true);
  DPP_STEP(c, 0x118, 0xf, true);  DPP_STEP(d, 0x118, 0xf, true);
  DPP_STEP(a, 0x142, 0xa, false); DPP_STEP(b, 0x142, 0xa, false);
  DPP_STEP(c, 0x142, 0xa, false); DPP_STEP(d, 0x142, 0xa, false);
  DPP_STEP(a, 0x143, 0xc, false); DPP_STEP(b, 0x143, 0xc, false);
  DPP_STEP(c, 0x143, 0xc, false); DPP_STEP(d, 0x143, 0xc, false);
  a = __int_as_float(__builtin_amdgcn_readlane(__float_as_int(a), 63));
  b = __int_as_float(__builtin_amdgcn_readlane(__float_as_int(b), 63));
  c = __int_as_float(__builtin_amdgcn_readlane(__float_as_int(c), 63));
  d = __int_as_float(__builtin_amdgcn_readlane(__float_as_int(d), 63));
}

// ---------------- kernel 0: centered qk0[h][d] = G[d] - mean_d(G)
__global__ __launch_bounds__(768) void k_qk(const float* __restrict__ wkv,
                                            const float* __restrict__ query,
                                            const float* __restrict__ gamma1,
                                            float* __restrict__ qk) {
  int h = blockIdx.x;
  int d = threadIdx.x;
  const float* wbase = wkv + (size_t)h * 96 * DD + d;
  const float* qb = query + h * 96;
  float acc = 0.f;
  #pragma unroll 8
  for (int i = 0; i < 96; ++i) acc = fmaf(qb[i], wbase[(size_t)i * DD], acc);
  acc *= 0.10206207261596577f * gamma1[d];   // 96^-0.5 * gamma1
  __shared__ float wsum[12];
  __shared__ float meanv;
  float v = acc;
  #pragma unroll
  for (int off = 1; off < 64; off <<= 1) v += __shfl_xor(v, off, 64);
  if ((d & 63) == 0) wsum[d >> 6] = v;
  __syncthreads();
  if (d == 0) {
    float s = 0.f;
    #pragma unroll
    for (int i = 0; i < 12; ++i) s += wsum[i];
    meanv = s * (1.f / 768.f);
  }
  __syncthreads();
  qk[h * DD + d] = acc - meanv;
}

// ---------------- kernel 1: triple-buffered global_load_lds pipeline, counted vmcnt
__global__ __launch_bounds__(256, 4) void k_main(
    const float* __restrict__ x, const float* __restrict__ qk,
    float* __restrict__ part) {
  const int tid  = threadIdx.x;
  const int lane = tid & 63;
  const int wave = tid >> 6;
  const int b     = blockIdx.x / CH;
  const int chunk = blockIdx.x - b * CH;
  const int h0 = wave * 2;

  __shared__ float lds[NB][TR][DD];

  float4 qA[3], qB[3];
  #pragma unroll
  for (int j = 0; j < 3; ++j) {
    qA[j] = *reinterpret_cast<const float4*>(qk + h0 * DD + j * 256 + lane * 4);
    qB[j] = *reinterpret_cast<const float4*>(qk + (h0 + 1) * DD + j * 256 + lane * 4);
  }

  float4 SA[3], SB[3];
  #pragma unroll
  for (int j = 0; j < 3; ++j) {
    SA[j] = make_float4(0.f, 0.f, 0.f, 0.f);
    SB[j] = make_float4(0.f, 0.f, 0.f, 0.f);
  }
  float seA = 0.f, seB = 0.f, chA = 0.f, chB = 0.f;

  const float* gbase = x + ((size_t)b * LL + (size_t)chunk * RPC) * DD;

  // stage tile T into buffer BUF: 3x 16B global->LDS DMA per thread (per wave:
  // 3 VMEM ops outstanding per staged tile)
  #define STAGE(T, BUF)                                                        \
    {                                                                          \
      const float* gt = gbase + (size_t)(T) * TR * DD;                         \
      float* lbase = &lds[(BUF)][0][0];                                        \
      _Pragma("unroll")                                                        \
      for (int i = 0; i < 3; ++i) {                                            \
        const float* src = gt + (size_t)(i * 256 + tid) * 4;                   \
        float* dst = lbase + (size_t)(i * 256 + wave * 64) * 4;                \
        __builtin_amdgcn_global_load_lds((const GLOBAL_AS uint32_t*)src,       \
                                         (LDS_AS uint32_t*)dst, 16, 0, 0);     \
      }                                                                        \
    }

  // prologue: fill 2 tiles ahead
  STAGE(0, 0)
  STAGE(1, 1)
  asm volatile("s_waitcnt vmcnt(3)" ::: "memory");  // tile 0 landed; tile 1 in flight
  __builtin_amdgcn_s_barrier();

  for (int t = 0; t < NT; ++t) {
    const int cur = t % NB;
    if (t + 2 < NT) STAGE(t + 2, (t + 2) % NB)   // flies across the next barrier

    #pragma unroll 1
    for (int r = 0; r < TR; ++r) {
      const float* row = &lds[cur][r][0];
      float4 c0 = *reinterpret_cast<const float4*>(row + lane * 4);
      float4 c1 = *reinterpret_cast<const float4*>(row + 256 + lane * 4);
      float4 c2 = *reinterpret_cast<const float4*>(row + 512 + lane * 4);

      float s1 = 0.f, s2 = 0.f, d0 = 0.f, d1 = 0.f;
#define ACC4(cv, J)                                                      \
      s1 += cv.x + cv.y + cv.z + cv.w;                                   \
      s2 = fmaf(cv.x, cv.x, s2); s2 = fmaf(cv.y, cv.y, s2);              \
      s2 = fmaf(cv.z, cv.z, s2); s2 = fmaf(cv.w, cv.w, s2);              \
      d0 = fmaf(cv.x, qA[J].x, d0); d0 = fmaf(cv.y, qA[J].y, d0);        \
      d0 = fmaf(cv.z, qA[J].z, d0); d0 = fmaf(cv.w, qA[J].w, d0);        \
      d1 = fmaf(cv.x, qB[J].x, d1); d1 = fmaf(cv.y, qB[J].y, d1);        \
      d1 = fmaf(cv.z, qB[J].z, d1); d1 = fmaf(cv.w, qB[J].w, d1);
      ACC4(c0, 0) ACC4(c1, 1) ACC4(c2, 2)
#undef ACC4

      wave_sum4(s1, s2, d0, d1);

      float mu   = s1 * (1.f / 768.f);
      float var  = fmaf(-mu, mu, s2 * (1.f / 768.f));
      float rstd = rsqrtf(var + 1e-5f);
      float sh   = -mu * rstd;
      float pe   = rstd * 1.44269504f;
      float p0 = exp2f(d0 * pe);
      float p1 = exp2f(d1 * pe);
      seA += p0; seB += p1;
      chA = fmaf(p0, sh, chA);
      chB = fmaf(p1, sh, chB);
      float a0 = p0 * rstd, a1 = p1 * rstd;

      SA[0].x = fmaf(a0, c0.x, SA[0].x); SA[0].y = fmaf(a0, c0.y, SA[0].y);
      SA[0].z = fmaf(a0, c0.z, SA[0].z); SA[0].w = fmaf(a0, c0.w, SA[0].w);
      SA[1].x = fmaf(a0, c1.x, SA[1].x); SA[1].y = fmaf(a0, c1.y, SA[1].y);
      SA[1].z = fmaf(a0, c1.z, SA[1].z); SA[1].w = fmaf(a0, c1.w, SA[1].w);
      SA[2].x = fmaf(a0, c2.x, SA[2].x); SA[2].y = fmaf(a0, c2.y, SA[2].y);
      SA[2].z = fmaf(a0, c2.z, SA[2].z); SA[2].w = fmaf(a0, c2.w, SA[2].w);

      SB[0].x = fmaf(a1, c0.x, SB[0].x); SB[0].y = fmaf(a1, c0.y, SB[0].y);
      SB[0].z = fmaf(a1, c0.z, SB[0].z); SB[0].w = fmaf(a1, c0.w, SB[0].w);
      SB[1].x = fmaf(a1, c1.x, SB[1].x); SB[1].y = fmaf(a1, c1.y, SB[1].y);
      SB[1].z = fmaf(a1, c1.z, SB[1].z); SB[1].w = fmaf(a1, c1.w, SB[1].w);
      SB[2].x = fmaf(a1, c2.x, SB[2].x); SB[2].y = fmaf(a1, c2.y, SB[2].y);
      SB[2].z = fmaf(a1, c2.z, SB[2].z); SB[2].w = fmaf(a1, c2.w, SB[2].w);
    }

    // counted drain: own next-tile stage landed; deepest stage may stay in flight
    if (t + 2 < NT) { asm volatile("s_waitcnt vmcnt(3)" ::: "memory"); }
    else            { asm volatile("s_waitcnt vmcnt(0)" ::: "memory"); }
    __builtin_amdgcn_s_barrier();   // raw barrier: no full vmcnt(0) drain
  }
  #undef STAGE

  size_t pb = (size_t)blockIdx.x * (HN * PSTR);
  float* pA = part + pb + (size_t)h0 * PSTR;
  float* pB = pA + PSTR;
  #pragma unroll
  for (int j = 0; j < 3; ++j) {
    float4 v = SA[j];
    v.x += chA; v.y += chA; v.z += chA; v.w += chA;
    *reinterpret_cast<float4*>(pA + j * 256 + lane * 4) = v;
    float4 w = SB[j];
    w.x += chB; w.y += chB; w.z += chB; w.w += chB;
    *reinterpret_cast<float4*>(pB + j * 256 + lane * 4) = w;
  }
  if (lane == 0) { pA[768] = seA; pB[768] = seB; }
}

// ---------------- kernel 2a: combine chunk partials -> xbar[b][h][768] (full-chip parallel)
__global__ __launch_bounds__(256) void k_red(const float* __restrict__ part,
                                             const float* __restrict__ gamma1,
                                             const float* __restrict__ beta1,
                                             float* __restrict__ xbar) {
  int b = blockIdx.x >> 3;
  int h = blockIdx.x & 7;
  int t = threadIdx.x;
  const float* pb = part + ((size_t)b * CH * HN + h) * PSTR;
  float se = 0.f, a0 = 0.f, a1 = 0.f, a2 = 0.f;
  for (int i = 0; i < CH; ++i) {
    const float* P = pb + (size_t)i * HN * PSTR;
    se += P[768];
    a0 += P[t];
    a1 += P[t + 256];
    a2 += P[t + 512];
  }
  float inv = 1.f / se;
  size_t ob = ((size_t)b * HN + h) * DD;
  xbar[ob + t]       = fmaf(gamma1[t],       a0 * inv, beta1[t]);
  xbar[ob + t + 256] = fmaf(gamma1[t + 256], a1 * inv, beta1[t + 256]);
  xbar[ob + t + 512] = fmaf(gamma1[t + 512], a2 * inv, beta1[t + 512]);
}

// ---------------- kernel 2b: V-projection + final LN
__global__ __launch_bounds__(1024) void k_out(
    const float* __restrict__ xbar, const float* __restrict__ wkv,
    const float* __restrict__ gamma2, const float* __restrict__ beta2,
    float* __restrict__ out) {
  int b = blockIdx.x;
  int t = threadIdx.x;
  __shared__ float xb[HN * DD];
  __shared__ float rs1[16], rs2[16];
  __shared__ float smu, srstd;
  #pragma unroll
  for (int k = 0; k < 6; ++k) xb[k * 1024 + t] = xbar[(size_t)b * HN * DD + k * 1024 + t];
  __syncthreads();

  float o = 0.f;
  if (t < DD) {
    int h = t / 96;
    const float4* wrow = reinterpret_cast<const float4*>(wkv + (size_t)(DD + t) * DD);
    const float* xh = xb + h * DD;
    float acc = 0.f;
    #pragma unroll 4
    for (int e = 0; e < 192; ++e) {
      float4 w = wrow[e];
      acc = fmaf(w.x, xh[e * 4 + 0], acc);
      acc = fmaf(w.y, xh[e * 4 + 1], acc);
      acc = fmaf(w.z, xh[e * 4 + 2], acc);
      acc = fmaf(w.w, xh[e * 4 + 3], acc);
    }
    o = acc;
  }

  float v1 = (t < DD) ? o : 0.f;
  float v2 = v1 * v1;
  #pragma unroll
  for (int off = 1; off < 64; off <<= 1) {
    v1 += __shfl_xor(v1, off, 64);
    v2 += __shfl_xor(v2, off, 64);
  }
  int wv = t >> 6, ln = t & 63;
  if (ln == 0) { rs1[wv] = v1; rs2[wv] = v2; }
  __syncthreads();
  if (t == 0) {
    float s1 = 0.f, s2 = 0.f;
    #pragma unroll
    for (int w = 0; w < 16; ++w) { s1 += rs1[w]; s2 += rs2[w]; }
    float mu = s1 * (1.f / 768.f);
    float var = fmaf(-mu, mu, s2 * (1.f / 768.f));
    smu = mu;
    srstd = rsqrtf(var + 1e-5f);
  }
  __syncthreads();
  if (t < DD)
    out[(size_t)b * DD + t] = fmaf((o - smu) * srstd, gamma2[t], beta2[t]);
}

extern "C" void kernel_launch(void* const* d_in, const int* in_sizes, int n_in,
                              void* d_out, int out_size, void* d_ws, size_t ws_size,
                              hipStream_t stream) {
  const float* x     = (const float*)d_in[0];
  const float* wkv   = (const float*)d_in[1];
  const float* query = (const float*)d_in[2];
  const float* g1    = (const float*)d_in[3];
  const float* b1    = (const float*)d_in[4];
  const float* g2    = (const float*)d_in[5];
  const float* b2    = (const float*)d_in[6];
  float* out = (float*)d_out;
  float* ws  = (float*)d_ws;

  float* qk   = ws;                                   // 6144 floats (pad to 8192)
  float* part = ws + 8192;                            // BB*CH*HN*PSTR floats (~25.3 MB)
  float* xbar = ws + 8192 + (size_t)BB * CH * HN * PSTR;  // BB*HN*DD floats (~786 KB)

  k_qk  <<<HN,      768,  0, stream>>>(wkv, query, g1, qk);
  k_main<<<BB * CH, 256,  0, stream>>>(x, qk, part);
  k_red <<<BB * HN, 256,  0, stream>>>(part, g1, b1, xbar);
  k_out <<<BB,      1024, 0, stream>>>(xbar, wkv, g2, b2, out);
}

// Round 7
// 181.307 us; speedup vs baseline: 1.9789x; 1.3908x over previous
//
#include <hip/hip_runtime.h>
#include <stdint.h>

#define DD 768
#define HN 8
#define LL 4096
#define BB 32
#define ROWS 64                 // rows per 1-wave block
#define NBLK (BB * LL / ROWS)   // 2048 blocks = exactly 8/CU x 256 CU
#define DEPTH 4                 // LDS ring slots (12 KB)
#define PSTR 772                // per-(block,head) partial: S[768], se at [768]

#define GLOBAL_AS __attribute__((address_space(1)))
#define LDS_AS    __attribute__((address_space(3)))

// ---- DPP wave64 sum helpers: 6 rounds, VALU-only ----
#define DPP_STEP(x, ctrl, rmask, bc)                                           \
  x += __int_as_float(__builtin_amdgcn_update_dpp(                             \
      0, __float_as_int(x), (ctrl), (rmask), 0xf, (bc)))

__device__ __forceinline__ void wave_sum4(float& a, float& b, float& c, float& d) {
  DPP_STEP(a, 0x111, 0xf, true);  DPP_STEP(b, 0x111, 0xf, true);
  DPP_STEP(c, 0x111, 0xf, true);  DPP_STEP(d, 0x111, 0xf, true);
  DPP_STEP(a, 0x112, 0xf, true);  DPP_STEP(b, 0x112, 0xf, true);
  DPP_STEP(c, 0x112, 0xf, true);  DPP_STEP(d, 0x112, 0xf, true);
  DPP_STEP(a, 0x114, 0xf, true);  DPP_STEP(b, 0x114, 0xf, true);
  DPP_STEP(c, 0x114, 0xf, true);  DPP_STEP(d, 0x114, 0xf, true);
  DPP_STEP(a, 0x118, 0xf, true);  DPP_STEP(b, 0x118, 0xf, true);
  DPP_STEP(c, 0x118, 0xf, true);  DPP_STEP(d, 0x118, 0xf, true);
  DPP_STEP(a, 0x142, 0xa, false); DPP_STEP(b, 0x142, 0xa, false);
  DPP_STEP(c, 0x142, 0xa, false); DPP_STEP(d, 0x142, 0xa, false);
  DPP_STEP(a, 0x143, 0xc, false); DPP_STEP(b, 0x143, 0xc, false);
  DPP_STEP(c, 0x143, 0xc, false); DPP_STEP(d, 0x143, 0xc, false);
  a = __int_as_float(__builtin_amdgcn_readlane(__float_as_int(a), 63));
  b = __int_as_float(__builtin_amdgcn_readlane(__float_as_int(b), 63));
  c = __int_as_float(__builtin_amdgcn_readlane(__float_as_int(c), 63));
  d = __int_as_float(__builtin_amdgcn_readlane(__float_as_int(d), 63));
}

__device__ __forceinline__ void wave_sum2(float& a, float& b) {
  DPP_STEP(a, 0x111, 0xf, true);  DPP_STEP(b, 0x111, 0xf, true);
  DPP_STEP(a, 0x112, 0xf, true);  DPP_STEP(b, 0x112, 0xf, true);
  DPP_STEP(a, 0x114, 0xf, true);  DPP_STEP(b, 0x114, 0xf, true);
  DPP_STEP(a, 0x118, 0xf, true);  DPP_STEP(b, 0x118, 0xf, true);
  DPP_STEP(a, 0x142, 0xa, false); DPP_STEP(b, 0x142, 0xa, false);
  DPP_STEP(a, 0x143, 0xc, false); DPP_STEP(b, 0x143, 0xc, false);
  a = __int_as_float(__builtin_amdgcn_readlane(__float_as_int(a), 63));
  b = __int_as_float(__builtin_amdgcn_readlane(__float_as_int(b), 63));
}

// ---------------- kernel 0: centered qk0[h][d] = G[d] - mean_d(G)
__global__ __launch_bounds__(768) void k_qk(const float* __restrict__ wkv,
                                            const float* __restrict__ query,
                                            const float* __restrict__ gamma1,
                                            float* __restrict__ qk) {
  int h = blockIdx.x;
  int d = threadIdx.x;
  const float* wbase = wkv + (size_t)h * 96 * DD + d;
  const float* qb = query + h * 96;
  float acc = 0.f;
  #pragma unroll 8
  for (int i = 0; i < 96; ++i) acc = fmaf(qb[i], wbase[(size_t)i * DD], acc);
  acc *= 0.10206207261596577f * gamma1[d];   // 96^-0.5 * gamma1
  __shared__ float wsum[12];
  __shared__ float meanv;
  float v = acc;
  #pragma unroll
  for (int off = 1; off < 64; off <<= 1) v += __shfl_xor(v, off, 64);
  if ((d & 63) == 0) wsum[d >> 6] = v;
  __syncthreads();
  if (d == 0) {
    float s = 0.f;
    #pragma unroll
    for (int i = 0; i < 12; ++i) s += wsum[i];
    meanv = s * (1.f / 768.f);
  }
  __syncthreads();
  qk[h * DD + d] = acc - meanv;
}

// ---------------- kernel 1: 1-wave blocks, 8 heads/wave, barrier-free ring pipeline
__global__ __launch_bounds__(64, 2) void k_main(
    const float* __restrict__ x, const float* __restrict__ qk,
    float* __restrict__ part) {
  const int lane = threadIdx.x;          // 0..63
  __shared__ float lds[DEPTH][DD];       // private ring, 12 KB

  // q fragments for all 8 heads: element j*256 + lane*4 + c
  float4 q[HN][3];
  #pragma unroll
  for (int h = 0; h < HN; ++h)
    #pragma unroll
    for (int j = 0; j < 3; ++j)
      q[h][j] = *reinterpret_cast<const float4*>(qk + h * DD + j * 256 + lane * 4);
  asm volatile("s_waitcnt vmcnt(0)" ::: "memory");  // q landed; vmcnt now tracks stages only

  float4 S[HN][3];
  float se[HN], ch[HN];
  #pragma unroll
  for (int h = 0; h < HN; ++h) {
    se[h] = 0.f; ch[h] = 0.f;
    #pragma unroll
    for (int j = 0; j < 3; ++j) S[h][j] = make_float4(0.f, 0.f, 0.f, 0.f);
  }

  const float* gbase = x + (size_t)blockIdx.x * ROWS * DD;

  // stage row R into ring slot R&3: 3x 16B global->LDS DMA (3 vmcnt events)
  #define STAGE(R)                                                             \
    {                                                                          \
      const float* gt = gbase + (size_t)(R) * DD;                              \
      float* db = &lds[(R) & (DEPTH - 1)][0];                                  \
      _Pragma("unroll")                                                        \
      for (int i = 0; i < 3; ++i)                                              \
        __builtin_amdgcn_global_load_lds(                                      \
            (const GLOBAL_AS uint32_t*)(gt + i * 256 + lane * 4),              \
            (LDS_AS uint32_t*)(db + i * 256), 16, 0, 0);                       \
    }

  #define COMPUTE(RR)                                                          \
    {                                                                          \
      const float* row = &lds[(RR) & (DEPTH - 1)][0];                          \
      float4 c0 = *reinterpret_cast<const float4*>(row + lane * 4);            \
      float4 c1 = *reinterpret_cast<const float4*>(row + 256 + lane * 4);      \
      float4 c2 = *reinterpret_cast<const float4*>(row + 512 + lane * 4);      \
      float s1 = 0.f, s2 = 0.f;                                                \
      float dt[HN];                                                            \
      _Pragma("unroll") for (int h = 0; h < HN; ++h) dt[h] = 0.f;              \
      ACC4(c0, 0) ACC4(c1, 1) ACC4(c2, 2)                                      \
      wave_sum4(s1, s2, dt[0], dt[1]);                                         \
      wave_sum4(dt[2], dt[3], dt[4], dt[5]);                                   \
      wave_sum2(dt[6], dt[7]);                                                 \
      float mu   = s1 * (1.f / 768.f);                                         \
      float var  = fmaf(-mu, mu, s2 * (1.f / 768.f));                          \
      float rstd = rsqrtf(var + 1e-5f);                                        \
      float sh   = -mu * rstd;                                                 \
      float pe   = rstd * 1.44269504f;                                         \
      _Pragma("unroll")                                                        \
      for (int h = 0; h < HN; ++h) {                                           \
        float p = exp2f(dt[h] * pe);                                           \
        se[h] += p;                                                            \
        ch[h] = fmaf(p, sh, ch[h]);                                            \
        float a = p * rstd;                                                    \
        S[h][0].x = fmaf(a, c0.x, S[h][0].x);                                  \
        S[h][0].y = fmaf(a, c0.y, S[h][0].y);                                  \
        S[h][0].z = fmaf(a, c0.z, S[h][0].z);                                  \
        S[h][0].w = fmaf(a, c0.w, S[h][0].w);                                  \
        S[h][1].x = fmaf(a, c1.x, S[h][1].x);                                  \
        S[h][1].y = fmaf(a, c1.y, S[h][1].y);                                  \
        S[h][1].z = fmaf(a, c1.z, S[h][1].z);                                  \
        S[h][1].w = fmaf(a, c1.w, S[h][1].w);                                  \
        S[h][2].x = fmaf(a, c2.x, S[h][2].x);                                  \
        S[h][2].y = fmaf(a, c2.y, S[h][2].y);                                  \
        S[h][2].z = fmaf(a, c2.z, S[h][2].z);                                  \
        S[h][2].w = fmaf(a, c2.w, S[h][2].w);                                  \
      }                                                                        \
    }

#define ACC4(cv, J)                                                            \
      s1 += cv.x + cv.y + cv.z + cv.w;                                         \
      s2 = fmaf(cv.x, cv.x, s2); s2 = fmaf(cv.y, cv.y, s2);                    \
      s2 = fmaf(cv.z, cv.z, s2); s2 = fmaf(cv.w, cv.w, s2);                    \
      _Pragma("unroll")                                                        \
      for (int h = 0; h < HN; ++h) {                                           \
        dt[h] = fmaf(cv.x, q[h][J].x, dt[h]);                                  \
        dt[h] = fmaf(cv.y, q[h][J].y, dt[h]);                                  \
        dt[h] = fmaf(cv.z, q[h][J].z, dt[h]);                                  \
        dt[h] = fmaf(cv.w, q[h][J].w, dt[h]);                                  \
      }

  // prologue: 3 rows in flight (9 loads)
  STAGE(0) STAGE(1) STAGE(2)

  #pragma unroll 1
  for (int r = 0; r <= ROWS - 4; ++r) {
    STAGE(r + 3)                                       // 12 outstanding
    asm volatile("s_waitcnt vmcnt(9)" ::: "memory");   // row r landed
    COMPUTE(r)
  }
  asm volatile("s_waitcnt vmcnt(6)" ::: "memory");
  COMPUTE(ROWS - 3)
  asm volatile("s_waitcnt vmcnt(3)" ::: "memory");
  COMPUTE(ROWS - 2)
  asm volatile("s_waitcnt vmcnt(0)" ::: "memory");
  COMPUTE(ROWS - 1)

  #undef ACC4
  #undef COMPUTE
  #undef STAGE

  // epilogue: wave-private partial write
  float* pb = part + (size_t)blockIdx.x * (HN * PSTR);
  #pragma unroll
  for (int h = 0; h < HN; ++h) {
    #pragma unroll
    for (int j = 0; j < 3; ++j) {
      float4 v = S[h][j];
      v.x += ch[h]; v.y += ch[h]; v.z += ch[h]; v.w += ch[h];
      *reinterpret_cast<float4*>(pb + h * PSTR + j * 256 + lane * 4) = v;
    }
  }
  if (lane == 0) {
    #pragma unroll
    for (int h = 0; h < HN; ++h) pb[h * PSTR + 768] = se[h];
  }
}

// ---------------- kernel 2a: combine 64 chunk partials -> xbar[b][h][768]
__global__ __launch_bounds__(256) void k_red(const float* __restrict__ part,
                                             const float* __restrict__ gamma1,
                                             const float* __restrict__ beta1,
                                             float* __restrict__ xbar) {
  int b = blockIdx.x >> 3;
  int h = blockIdx.x & 7;
  int t = threadIdx.x;
  const int CPB = LL / ROWS;   // 64 chunks per batch
  const float* pb = part + ((size_t)b * CPB * HN + h) * PSTR;
  float se = 0.f, a0 = 0.f, a1 = 0.f, a2 = 0.f;
  for (int i = 0; i < CPB; ++i) {
    const float* P = pb + (size_t)i * HN * PSTR;
    se += P[768];
    a0 += P[t];
    a1 += P[t + 256];
    a2 += P[t + 512];
  }
  float inv = 1.f / se;
  size_t ob = ((size_t)b * HN + h) * DD;
  xbar[ob + t]       = fmaf(gamma1[t],       a0 * inv, beta1[t]);
  xbar[ob + t + 256] = fmaf(gamma1[t + 256], a1 * inv, beta1[t + 256]);
  xbar[ob + t + 512] = fmaf(gamma1[t + 512], a2 * inv, beta1[t + 512]);
}

// ---------------- kernel 2b: V-projection (96 blocks: 32 b x 3 g-chunks)
__global__ __launch_bounds__(256) void k_proj(
    const float* __restrict__ xbar, const float* __restrict__ wkv,
    float* __restrict__ outp) {
  int b  = blockIdx.x / 3;
  int gc = blockIdx.x % 3;
  int t  = threadIdx.x;
  __shared__ float xb[HN * DD];
  #pragma unroll
  for (int k = 0; k < 24; ++k) xb[k * 256 + t] = xbar[(size_t)b * HN * DD + k * 256 + t];
  __syncthreads();

  int g = gc * 256 + t;
  int h = g / 96;
  const float4* wrow = reinterpret_cast<const float4*>(wkv + (size_t)(DD + g) * DD);
  const float* xh = xb + h * DD;
  float acc = 0.f;
  #pragma unroll 4
  for (int e = 0; e < 192; ++e) {
    float4 w = wrow[e];
    acc = fmaf(w.x, xh[e * 4 + 0], acc);
    acc = fmaf(w.y, xh[e * 4 + 1], acc);
    acc = fmaf(w.z, xh[e * 4 + 2], acc);
    acc = fmaf(w.w, xh[e * 4 + 3], acc);
  }
  outp[(size_t)b * DD + g] = acc;
}

// ---------------- kernel 2c: final LN over 768
__global__ __launch_bounds__(768) void k_ln2(
    const float* __restrict__ outp, const float* __restrict__ gamma2,
    const float* __restrict__ beta2, float* __restrict__ out) {
  int b = blockIdx.x;
  int t = threadIdx.x;
  __shared__ float rs1[12], rs2[12];
  __shared__ float smu, srstd;
  float o = outp[(size_t)b * DD + t];
  float v1 = o, v2 = o * o;
  #pragma unroll
  for (int off = 1; off < 64; off <<= 1) {
    v1 += __shfl_xor(v1, off, 64);
    v2 += __shfl_xor(v2, off, 64);
  }
  int wv = t >> 6, ln = t & 63;
  if (ln == 0) { rs1[wv] = v1; rs2[wv] = v2; }
  __syncthreads();
  if (t == 0) {
    float s1 = 0.f, s2 = 0.f;
    #pragma unroll
    for (int w = 0; w < 12; ++w) { s1 += rs1[w]; s2 += rs2[w]; }
    float mu = s1 * (1.f / 768.f);
    float var = fmaf(-mu, mu, s2 * (1.f / 768.f));
    smu = mu;
    srstd = rsqrtf(var + 1e-5f);
  }
  __syncthreads();
  out[(size_t)b * DD + t] = fmaf((o - smu) * srstd, gamma2[t], beta2[t]);
}

extern "C" void kernel_launch(void* const* d_in, const int* in_sizes, int n_in,
                              void* d_out, int out_size, void* d_ws, size_t ws_size,
                              hipStream_t stream) {
  const float* x     = (const float*)d_in[0];
  const float* wkv   = (const float*)d_in[1];
  const float* query = (const float*)d_in[2];
  const float* g1    = (const float*)d_in[3];
  const float* b1    = (const float*)d_in[4];
  const float* g2    = (const float*)d_in[5];
  const float* b2    = (const float*)d_in[6];
  float* out = (float*)d_out;
  float* ws  = (float*)d_ws;

  float* qk   = ws;                                    // 6144 floats (pad 8192)
  float* part = ws + 8192;                             // NBLK*HN*PSTR (~50.6 MB)
  float* xbar = part + (size_t)NBLK * HN * PSTR;       // BB*HN*DD
  float* outp = xbar + (size_t)BB * HN * DD;           // BB*DD

  k_qk  <<<HN,      768, 0, stream>>>(wkv, query, g1, qk);
  k_main<<<NBLK,    64,  0, stream>>>(x, qk, part);
  k_red <<<BB * HN, 256, 0, stream>>>(part, g1, b1, xbar);
  k_proj<<<BB * 3,  256, 0, stream>>>(xbar, wkv, outp);
  k_ln2 <<<BB,      768, 0, stream>>>(outp, g2, b2, out);
}